// Round 2
// baseline (483.066 us; speedup 1.0000x reference)
//
#include <hip/hip_runtime.h>

// Problem constants (reference: B,T,D,O = 16,1024,1024,10; T==D required)
#define BB 16
#define TT 1024
#define DD 1024
#define OO 10

// ---------------------------------------------------------------------------
// Shared GEMM template for both passes:
//   Y[b][o][t] = (sum_d X[b][t][d] * Wsel[o][d] + bias[o]) * scale
// where Wsel = Wt (shared, K1) or Wt + b*O*D (per-batch w_x, K3).
//
// Mapping: grid (T/16, B), block 256 = 4 waves.
//  - Block covers 16 rows t. Each WAVE covers all 16 rows but one quarter
//    of D (256 elements) -> per-wave partials combined via tiny LDS.
//  - Within a wave: lane = g*8 + l. Group g (8 groups) owns rows t0+g and
//    t0+8+g; lane-slice l owns d = dbase + it*32 + l*4 (float4).
//  - Dot spans only 8 lanes -> 3-level __shfl_down(width=8) reduction
//    (vs 6-level over 64 lanes: was ~40% overhead on the LDS pipe).
//  - W read straight from global: 40 KB, L2-resident, 8-way lane dedup
//    coalesces each read to 128 B. No big LDS staging, no staging barrier,
//    no 4-blocks/CU LDS occupancy cap.
// ---------------------------------------------------------------------------
template <bool BIAS>
__global__ __launch_bounds__(256, 4) void gemm10_kernel(
    const float* __restrict__ X,   // (B,T,D)
    const float* __restrict__ Wt,  // (O,D) or (B,O,D)
    const float* __restrict__ bias,
    float* __restrict__ Y,         // (B,O,T)
    float scale, int perBatchW)
{
    const int b    = blockIdx.y;
    const int t0   = blockIdx.x * 16;
    const int tid  = threadIdx.x;
    const int w    = tid >> 6;       // wave 0..3 -> d quarter
    const int lane = tid & 63;
    const int l    = lane & 7;       // d-slice within row
    const int g    = lane >> 3;      // row group 0..7
    const int dofs = w * 256 + l * 4;

    const float* Wb = Wt + (size_t)(perBatchW ? b : 0) * (OO * DD) + dofs;
    const float* x0 = X + ((size_t)b * TT + t0) * DD + dofs;
    const float* xa_p = x0 + (size_t)g * DD;        // row t0+g
    const float* xb_p = x0 + (size_t)(8 + g) * DD;  // row t0+8+g

    float acc[2][OO];
#pragma unroll
    for (int j = 0; j < 2; ++j)
#pragma unroll
        for (int o = 0; o < OO; ++o) acc[j][o] = 0.f;

#pragma unroll
    for (int it = 0; it < 8; ++it) {
        const int d = it * 32;
        const float4 xa = *(const float4*)(xa_p + d);
        const float4 xb = *(const float4*)(xb_p + d);
#pragma unroll
        for (int o = 0; o < OO; ++o) {
            const float4 wv = *(const float4*)(Wb + (size_t)o * DD + d);
            acc[0][o] += xa.x * wv.x + xa.y * wv.y + xa.z * wv.z + xa.w * wv.w;
            acc[1][o] += xb.x * wv.x + xb.y * wv.y + xb.z * wv.z + xb.w * wv.w;
        }
    }

    // 3-level reduction within each 8-lane group, then cross-wave via LDS.
    __shared__ float part[4][16][OO];  // 2.5 KB
#pragma unroll
    for (int j = 0; j < 2; ++j) {
#pragma unroll
        for (int o = 0; o < OO; ++o) {
            float v = acc[j][o];
            v += __shfl_down(v, 4, 8);
            v += __shfl_down(v, 2, 8);
            v += __shfl_down(v, 1, 8);
            if (l == 0) part[w][j * 8 + g][o] = v;
        }
    }
    __syncthreads();

    if (tid < 16 * OO) {
        const int row = tid / OO;
        const int o   = tid % OO;
        float v = part[0][row][o] + part[1][row][o] +
                  part[2][row][o] + part[3][row][o];
        if (BIAS) v = (v + bias[o]) * scale;
        Y[((size_t)b * OO + o) * TT + (t0 + row)] = v;
    }
}

// ---------------------------------------------------------------------------
// K2: in-place softmax along T for each (b,o) column (contiguous, length 1024).
// ---------------------------------------------------------------------------
__global__ __launch_bounds__(256) void softmax_kernel(float* __restrict__ s)
{
    float* col = s + (size_t)blockIdx.x * TT;
    const int tid  = threadIdx.x;
    const int wave = tid >> 6;
    const int lane = tid & 63;

    float4 v = *(const float4*)(col + tid * 4);

    __shared__ float sm[4];
    __shared__ float ss[4];

    float m = fmaxf(fmaxf(v.x, v.y), fmaxf(v.z, v.w));
#pragma unroll
    for (int off = 32; off > 0; off >>= 1) m = fmaxf(m, __shfl_down(m, off, 64));
    if (lane == 0) sm[wave] = m;
    __syncthreads();
    m = fmaxf(fmaxf(sm[0], sm[1]), fmaxf(sm[2], sm[3]));

    float e0 = __expf(v.x - m), e1 = __expf(v.y - m);
    float e2 = __expf(v.z - m), e3 = __expf(v.w - m);
    float sum = e0 + e1 + e2 + e3;
#pragma unroll
    for (int off = 32; off > 0; off >>= 1) sum += __shfl_down(sum, off, 64);
    if (lane == 0) ss[wave] = sum;
    __syncthreads();
    const float inv = 1.0f / (ss[0] + ss[1] + ss[2] + ss[3]);

    *(float4*)(col + tid * 4) = make_float4(e0 * inv, e1 * inv, e2 * inv, e3 * inv);
}

extern "C" void kernel_launch(void* const* d_in, const int* in_sizes, int n_in,
                              void* d_out, int out_size, void* d_ws, size_t ws_size,
                              hipStream_t stream)
{
    const float* logits = (const float*)d_in[0];
    // d_in[1] = decision — unused by the forward math
    const float* W    = (const float*)d_in[2];
    const float* bias = (const float*)d_in[3];
    float* out    = (float*)d_out;
    float* scores = (float*)d_ws;  // B*O*T floats = 655 KB (softmax in-place)

    dim3 grid(TT / 16, BB);
    // K1: scores[b][o][t] = (logits[b,t,:] . W[o,:] + bias[o]) / O
    gemm10_kernel<true><<<grid, 256, 0, stream>>>(logits, W, bias, scores,
                                                  1.0f / OO, 0);
    // K2: softmax over t for each (b,o)
    softmax_kernel<<<BB * OO, 256, 0, stream>>>(scores);
    // K3: out[b][o][t] = logits[b,t,:] . w_x[b,:,o]  (w_x stored as (B,O,T))
    gemm10_kernel<false><<<grid, 256, 0, stream>>>(logits, scores, nullptr, out,
                                                   1.0f, 1);
}

// Round 3
// 127.999 us; speedup vs baseline: 3.7740x; 3.7740x over previous
//
#include <hip/hip_runtime.h>

// Problem constants (reference: B,T,D,O = 16,1024,1024,10; T==D required)
#define BB 16
#define TT 1024
#define DD 1024
#define OO 10

// ---------------------------------------------------------------------------
// Shared GEMM for both passes:
//   Y[b][o][t] = (sum_d X[b][t][d] * Wsel[o][d] + bias[o]) * scale
// Wsel = Wt (shared, K1) or Wt + b*O*D (per-batch w_x, K3).
//
// Mapping: grid (T/16, B), block 256 = 4 waves.
//  - Block covers 16 rows t. Each WAVE covers all 16 rows but one quarter
//    of D (256 elems); per-wave partials combined via 2.5 KB LDS.
//  - lane = g*8 + l: group g (0..7) owns rows t0+g and t0+8+g; slice l
//    owns d = w*256 + it*32 + l*4 (float4) -> wave's 8 slices x 16 B = 128 B
//    contiguous per row, coalesced.
//  - Dot spans 8 lanes -> 3-level __shfl_down(width=8).
//  - W read from global (40 KB, L2-resident; 8-way lane dedup -> 128 B/instr).
//
// R2 post-mortem: __launch_bounds__(256,4) + full unroll spilled the
// accumulators (284 MB scratch writes, VALUBusy 2.7%). Fix: no occupancy
// hint, #pragma unroll 1 on the K-loop so only one iteration's 10 W float4
// loads are live, manual 1-deep prefetch of the next logits chunk.
// ---------------------------------------------------------------------------
template <bool BIAS>
__global__ __launch_bounds__(256) void gemm10_kernel(
    const float* __restrict__ X,   // (B,T,D)
    const float* __restrict__ Wt,  // (O,D) or (B,O,D)
    const float* __restrict__ bias,
    float* __restrict__ Y,         // (B,O,T)
    float scale, int perBatchW)
{
    const int b    = blockIdx.y;
    const int t0   = blockIdx.x * 16;
    const int tid  = threadIdx.x;
    const int w    = tid >> 6;       // wave 0..3 -> d quarter
    const int lane = tid & 63;
    const int l    = lane & 7;       // d-slice within row
    const int g    = lane >> 3;      // row group 0..7
    const int dofs = w * 256 + l * 4;

    const float* Wb = Wt + (size_t)(perBatchW ? b : 0) * (OO * DD) + dofs;
    const float* x0 = X + ((size_t)b * TT + t0) * DD + dofs;
    const float* xa_p = x0 + (size_t)g * DD;        // row t0+g
    const float* xb_p = x0 + (size_t)(8 + g) * DD;  // row t0+8+g

    float acc[2][OO];
#pragma unroll
    for (int j = 0; j < 2; ++j)
#pragma unroll
        for (int o = 0; o < OO; ++o) acc[j][o] = 0.f;

    float4 xa = *(const float4*)xa_p;   // prefetch it=0
    float4 xb = *(const float4*)xb_p;

#pragma unroll 1
    for (int it = 0; it < 8; ++it) {
        const float4 xa_c = xa;
        const float4 xb_c = xb;
        if (it < 7) {                   // prefetch it+1 while FMAs run
            xa = *(const float4*)(xa_p + (it + 1) * 32);
            xb = *(const float4*)(xb_p + (it + 1) * 32);
        }
        const float* Wi = Wb + it * 32;
#pragma unroll
        for (int o = 0; o < OO; ++o) {
            const float4 wv = *(const float4*)(Wi + (size_t)o * DD);
            acc[0][o] += xa_c.x * wv.x + xa_c.y * wv.y + xa_c.z * wv.z + xa_c.w * wv.w;
            acc[1][o] += xb_c.x * wv.x + xb_c.y * wv.y + xb_c.z * wv.z + xb_c.w * wv.w;
        }
    }

    // 3-level reduction within each 8-lane group, then cross-wave via LDS.
    __shared__ float part[4][16][OO];  // 2.5 KB
#pragma unroll
    for (int j = 0; j < 2; ++j) {
#pragma unroll
        for (int o = 0; o < OO; ++o) {
            float v = acc[j][o];
            v += __shfl_down(v, 4, 8);
            v += __shfl_down(v, 2, 8);
            v += __shfl_down(v, 1, 8);
            if (l == 0) part[w][j * 8 + g][o] = v;
        }
    }
    __syncthreads();

    if (tid < 16 * OO) {
        const int row = tid / OO;
        const int o   = tid % OO;
        float v = part[0][row][o] + part[1][row][o] +
                  part[2][row][o] + part[3][row][o];
        if (BIAS) v = (v + bias[o]) * scale;
        Y[((size_t)b * OO + o) * TT + (t0 + row)] = v;
    }
}

// ---------------------------------------------------------------------------
// K2: in-place softmax along T for each (b,o) column (contiguous, length 1024).
// ---------------------------------------------------------------------------
__global__ __launch_bounds__(256) void softmax_kernel(float* __restrict__ s)
{
    float* col = s + (size_t)blockIdx.x * TT;
    const int tid  = threadIdx.x;
    const int wave = tid >> 6;
    const int lane = tid & 63;

    float4 v = *(const float4*)(col + tid * 4);

    __shared__ float sm[4];
    __shared__ float ss[4];

    float m = fmaxf(fmaxf(v.x, v.y), fmaxf(v.z, v.w));
#pragma unroll
    for (int off = 32; off > 0; off >>= 1) m = fmaxf(m, __shfl_down(m, off, 64));
    if (lane == 0) sm[wave] = m;
    __syncthreads();
    m = fmaxf(fmaxf(sm[0], sm[1]), fmaxf(sm[2], sm[3]));

    float e0 = __expf(v.x - m), e1 = __expf(v.y - m);
    float e2 = __expf(v.z - m), e3 = __expf(v.w - m);
    float sum = e0 + e1 + e2 + e3;
#pragma unroll
    for (int off = 32; off > 0; off >>= 1) sum += __shfl_down(sum, off, 64);
    if (lane == 0) ss[wave] = sum;
    __syncthreads();
    const float inv = 1.0f / (ss[0] + ss[1] + ss[2] + ss[3]);

    *(float4*)(col + tid * 4) = make_float4(e0 * inv, e1 * inv, e2 * inv, e3 * inv);
}

extern "C" void kernel_launch(void* const* d_in, const int* in_sizes, int n_in,
                              void* d_out, int out_size, void* d_ws, size_t ws_size,
                              hipStream_t stream)
{
    const float* logits = (const float*)d_in[0];
    // d_in[1] = decision — unused by the forward math
    const float* W    = (const float*)d_in[2];
    const float* bias = (const float*)d_in[3];
    float* out    = (float*)d_out;
    float* scores = (float*)d_ws;  // B*O*T floats = 655 KB (softmax in-place)

    dim3 grid(TT / 16, BB);
    // K1: scores[b][o][t] = (logits[b,t,:] . W[o,:] + bias[o]) / O
    gemm10_kernel<true><<<grid, 256, 0, stream>>>(logits, W, bias, scores,
                                                  1.0f / OO, 0);
    // K2: softmax over t for each (b,o)
    softmax_kernel<<<BB * OO, 256, 0, stream>>>(scores);
    // K3: out[b][o][t] = logits[b,t,:] . w_x[b,:,o]  (w_x stored as (B,O,T))
    gemm10_kernel<false><<<grid, 256, 0, stream>>>(logits, scores, nullptr, out,
                                                   1.0f, 1);
}

// Round 4
// 122.470 us; speedup vs baseline: 3.9444x; 1.0451x over previous
//
#include <hip/hip_runtime.h>

// Problem constants (reference: B,T,D,O = 16,1024,1024,10; T==D required)
#define BB 16
#define TT 1024
#define DD 1024
#define OO 10

// ---------------------------------------------------------------------------
// Shared GEMM for both passes:
//   Y[b][o][t] = (sum_d X[b][t][d] * Wsel[o][d] + bias[o]) * scale
// Wsel = Wt (shared, K1) or Wt + b*O*D (per-batch w_x, K3).
//
// Mapping: grid (T/16, B), block 256 = 4 waves.
//  - W (40 KB) staged to LDS once per block (coalesced float4, conflict-free).
//    Removes the per-iteration global->L2 latency chain that left R3 at
//    ~39 us/gemm with VALUBusy ~3%.
//  - Block covers 16 rows t. Wave w covers all 16 rows x one quarter of D.
//  - lane = g*8 + l: group g owns rows t0+g, t0+8+g; slice l owns
//    d = w*256 + it*32 + l*4 (float4). Wave x-load = 8 rows x 128 B, coalesced.
//  - x prefetched 2 iterations deep -> steady-state loop touches only LDS.
//  - Dot spans 8 lanes -> 3-level __shfl_down(width=8) epilogue (cheap),
//    cross-wave combine via 2.5 KB LDS.
// R2 lesson: no occupancy hint, outer loop #pragma unroll 1 (spill killer).
// ---------------------------------------------------------------------------
template <bool BIAS>
__global__ __launch_bounds__(256) void gemm10_kernel(
    const float* __restrict__ X,   // (B,T,D)
    const float* __restrict__ Wt,  // (O,D) or (B,O,D)
    const float* __restrict__ bias,
    float* __restrict__ Y,         // (B,O,T)
    float scale, int perBatchW)
{
    __shared__ float sW[OO * DD];       // 40 KB
    __shared__ float part[4][16][OO];   // 2.5 KB

    const int b   = blockIdx.y;
    const int t0  = blockIdx.x * 16;
    const int tid = threadIdx.x;

    // ---- stage W -> LDS (2560 float4, 10 per thread, coalesced) ----
    {
        const float4* src = (const float4*)(Wt + (size_t)(perBatchW ? b : 0) * (OO * DD));
        float4* dst = (float4*)sW;
#pragma unroll
        for (int c = 0; c < 10; ++c)
            dst[c * 256 + tid] = src[c * 256 + tid];
    }
    __syncthreads();

    const int w    = tid >> 6;       // wave 0..3 -> d quarter
    const int lane = tid & 63;
    const int l    = lane & 7;       // d-slice within row
    const int g    = lane >> 3;      // row group 0..7
    const int dofs = w * 256 + l * 4;

    const float* xa_p = X + ((size_t)b * TT + t0 + g) * DD + dofs;  // row t0+g
    const float* xb_p = xa_p + (size_t)8 * DD;                       // row t0+8+g
    const float* sWl  = sW + dofs;

    float acc[2][OO];
#pragma unroll
    for (int j = 0; j < 2; ++j)
#pragma unroll
        for (int o = 0; o < OO; ++o) acc[j][o] = 0.f;

    // 2-deep prefetch of the logits slices
    float4 a0 = *(const float4*)(xa_p +  0), b0 = *(const float4*)(xb_p +  0);
    float4 a1 = *(const float4*)(xa_p + 32), b1 = *(const float4*)(xb_p + 32);

#pragma unroll 1
    for (int it = 0; it < 8; it += 2) {
        float4 ca = a0, cb = b0;
        if (it < 6) {
            a0 = *(const float4*)(xa_p + (it + 2) * 32);
            b0 = *(const float4*)(xb_p + (it + 2) * 32);
        }
        {
            const float* wp = sWl + it * 32;
#pragma unroll
            for (int o = 0; o < OO; ++o) {
                const float4 wv = *(const float4*)(wp + o * DD);
                acc[0][o] += ca.x * wv.x + ca.y * wv.y + ca.z * wv.z + ca.w * wv.w;
                acc[1][o] += cb.x * wv.x + cb.y * wv.y + cb.z * wv.z + cb.w * wv.w;
            }
        }
        ca = a1; cb = b1;
        if (it < 5) {
            a1 = *(const float4*)(xa_p + (it + 3) * 32);
            b1 = *(const float4*)(xb_p + (it + 3) * 32);
        }
        {
            const float* wp = sWl + (it + 1) * 32;
#pragma unroll
            for (int o = 0; o < OO; ++o) {
                const float4 wv = *(const float4*)(wp + o * DD);
                acc[0][o] += ca.x * wv.x + ca.y * wv.y + ca.z * wv.z + ca.w * wv.w;
                acc[1][o] += cb.x * wv.x + cb.y * wv.y + cb.z * wv.z + cb.w * wv.w;
            }
        }
    }

    // 3-level reduction within each 8-lane group, then cross-wave via LDS.
#pragma unroll
    for (int j = 0; j < 2; ++j) {
#pragma unroll
        for (int o = 0; o < OO; ++o) {
            float v = acc[j][o];
            v += __shfl_down(v, 4, 8);
            v += __shfl_down(v, 2, 8);
            v += __shfl_down(v, 1, 8);
            if (l == 0) part[w][j * 8 + g][o] = v;
        }
    }
    __syncthreads();

    if (tid < 16 * OO) {
        const int row = tid / OO;
        const int o   = tid % OO;
        float v = part[0][row][o] + part[1][row][o] +
                  part[2][row][o] + part[3][row][o];
        if (BIAS) v = (v + bias[o]) * scale;
        Y[((size_t)b * OO + o) * TT + (t0 + row)] = v;
    }
}

// ---------------------------------------------------------------------------
// K2: in-place softmax along T for each (b,o) column (contiguous, length 1024).
// ---------------------------------------------------------------------------
__global__ __launch_bounds__(256) void softmax_kernel(float* __restrict__ s)
{
    float* col = s + (size_t)blockIdx.x * TT;
    const int tid  = threadIdx.x;
    const int wave = tid >> 6;
    const int lane = tid & 63;

    float4 v = *(const float4*)(col + tid * 4);

    __shared__ float sm[4];
    __shared__ float ss[4];

    float m = fmaxf(fmaxf(v.x, v.y), fmaxf(v.z, v.w));
#pragma unroll
    for (int off = 32; off > 0; off >>= 1) m = fmaxf(m, __shfl_down(m, off, 64));
    if (lane == 0) sm[wave] = m;
    __syncthreads();
    m = fmaxf(fmaxf(sm[0], sm[1]), fmaxf(sm[2], sm[3]));

    float e0 = __expf(v.x - m), e1 = __expf(v.y - m);
    float e2 = __expf(v.z - m), e3 = __expf(v.w - m);
    float sum = e0 + e1 + e2 + e3;
#pragma unroll
    for (int off = 32; off > 0; off >>= 1) sum += __shfl_down(sum, off, 64);
    if (lane == 0) ss[wave] = sum;
    __syncthreads();
    const float inv = 1.0f / (ss[0] + ss[1] + ss[2] + ss[3]);

    *(float4*)(col + tid * 4) = make_float4(e0 * inv, e1 * inv, e2 * inv, e3 * inv);
}

extern "C" void kernel_launch(void* const* d_in, const int* in_sizes, int n_in,
                              void* d_out, int out_size, void* d_ws, size_t ws_size,
                              hipStream_t stream)
{
    const float* logits = (const float*)d_in[0];
    // d_in[1] = decision — unused by the forward math
    const float* W    = (const float*)d_in[2];
    const float* bias = (const float*)d_in[3];
    float* out    = (float*)d_out;
    float* scores = (float*)d_ws;  // B*O*T floats = 655 KB (softmax in-place)

    dim3 grid(TT / 16, BB);
    // K1: scores[b][o][t] = (logits[b,t,:] . W[o,:] + bias[o]) / O
    gemm10_kernel<true><<<grid, 256, 0, stream>>>(logits, W, bias, scores,
                                                  1.0f / OO, 0);
    // K2: softmax over t for each (b,o)
    softmax_kernel<<<BB * OO, 256, 0, stream>>>(scores);
    // K3: out[b][o][t] = logits[b,t,:] . w_x[b,:,o]  (w_x stored as (B,O,T))
    gemm10_kernel<false><<<grid, 256, 0, stream>>>(logits, scores, nullptr, out,
                                                   1.0f, 1);
}

// Round 5
// 120.741 us; speedup vs baseline: 4.0008x; 1.0143x over previous
//
#include <hip/hip_runtime.h>

// Problem constants (reference: B,T,D,O = 16,1024,1024,10; T==D required)
#define BB 16
#define TT 1024
#define DD 1024
#define OO 10

// ---------------------------------------------------------------------------
// Shared GEMM for both passes:
//   Y[b][o][t] = (sum_d X[b][t][d] * Wsel[o][d] + bias[o]) * scale
// Wsel = Wt (shared, K1) or Wt + b*O*D (per-batch w_x, K3).
//
// Mapping: grid (T/32, B), block 256 = 4 waves, 32 rows t per block.
//  - W (40 KB) staged to LDS once per block (coalesced float4).
//  - Wave w covers all 32 rows x one quarter of D (256 elems).
//  - lane = g*8 + l: group g owns rows t0+g+8j (j=0..3); slice l owns
//    d = w*256 + it*32 + l*4 (float4).
//  - Each W LDS read (10 ds_read_b128/iter) feeds 4 rows -> 16 v_fma per
//    ds_read (was 8 in R4): per-iter issue ~400 cy, so the 2-deep x
//    prefetch spans ~800 cy ~= HBM latency.
//  - Dot spans 8 lanes -> 3-level __shfl_down(width=8), cross-wave combine
//    via 5 KB LDS.
// R2 lesson: no occupancy-hint launch_bounds, outer loop unroll 1 with
// manual prefetch rotation (spill killer).
// ---------------------------------------------------------------------------
template <bool BIAS>
__global__ __launch_bounds__(256) void gemm10_kernel(
    const float* __restrict__ X,   // (B,T,D)
    const float* __restrict__ Wt,  // (O,D) or (B,O,D)
    const float* __restrict__ bias,
    float* __restrict__ Y,         // (B,O,T)
    float scale, int perBatchW)
{
    __shared__ float sW[OO * DD];       // 40 KB
    __shared__ float part[4][32][OO];   // 5 KB

    const int b   = blockIdx.y;
    const int t0  = blockIdx.x * 32;
    const int tid = threadIdx.x;

    // ---- stage W -> LDS (2560 float4, 10 per thread, coalesced) ----
    {
        const float4* src = (const float4*)(Wt + (size_t)(perBatchW ? b : 0) * (OO * DD));
        float4* dst = (float4*)sW;
#pragma unroll
        for (int c = 0; c < 10; ++c)
            dst[c * 256 + tid] = src[c * 256 + tid];
    }
    __syncthreads();

    const int w    = tid >> 6;       // wave 0..3 -> d quarter
    const int lane = tid & 63;
    const int l    = lane & 7;       // d-slice within row
    const int g    = lane >> 3;      // row group 0..7
    const int dofs = w * 256 + l * 4;

    const float* xp[4];
#pragma unroll
    for (int j = 0; j < 4; ++j)
        xp[j] = X + ((size_t)b * TT + t0 + g + 8 * j) * DD + dofs;
    const float* sWl = sW + dofs;

    float acc[4][OO];
#pragma unroll
    for (int j = 0; j < 4; ++j)
#pragma unroll
        for (int o = 0; o < OO; ++o) acc[j][o] = 0.f;

    // 2-deep prefetch of the logits slices (4 rows x 2 iters = 32 VGPRs)
    float4 x0[4], x1[4];
#pragma unroll
    for (int j = 0; j < 4; ++j) {
        x0[j] = *(const float4*)(xp[j]);
        x1[j] = *(const float4*)(xp[j] + 32);
    }

#pragma unroll 1
    for (int it = 0; it < 8; it += 2) {
        float4 c0[4];
#pragma unroll
        for (int j = 0; j < 4; ++j) c0[j] = x0[j];
        if (it < 6) {
#pragma unroll
            for (int j = 0; j < 4; ++j)
                x0[j] = *(const float4*)(xp[j] + (it + 2) * 32);
        }
        {
            const float* wp = sWl + it * 32;
#pragma unroll
            for (int o = 0; o < OO; ++o) {
                const float4 wv = *(const float4*)(wp + o * DD);
#pragma unroll
                for (int j = 0; j < 4; ++j)
                    acc[j][o] += c0[j].x * wv.x + c0[j].y * wv.y +
                                 c0[j].z * wv.z + c0[j].w * wv.w;
            }
        }
#pragma unroll
        for (int j = 0; j < 4; ++j) c0[j] = x1[j];
        if (it < 5) {
#pragma unroll
            for (int j = 0; j < 4; ++j)
                x1[j] = *(const float4*)(xp[j] + (it + 3) * 32);
        }
        {
            const float* wp = sWl + (it + 1) * 32;
#pragma unroll
            for (int o = 0; o < OO; ++o) {
                const float4 wv = *(const float4*)(wp + o * DD);
#pragma unroll
                for (int j = 0; j < 4; ++j)
                    acc[j][o] += c0[j].x * wv.x + c0[j].y * wv.y +
                                 c0[j].z * wv.z + c0[j].w * wv.w;
            }
        }
    }

    // 3-level reduction within each 8-lane group, then cross-wave via LDS.
#pragma unroll
    for (int j = 0; j < 4; ++j) {
#pragma unroll
        for (int o = 0; o < OO; ++o) {
            float v = acc[j][o];
            v += __shfl_down(v, 4, 8);
            v += __shfl_down(v, 2, 8);
            v += __shfl_down(v, 1, 8);
            if (l == 0) part[w][j * 8 + g][o] = v;
        }
    }
    __syncthreads();

    // 32 rows x 10 o = 320 outputs; 256 threads -> loop
    for (int idx = tid; idx < 32 * OO; idx += 256) {
        const int row = idx / OO;
        const int o   = idx % OO;
        float v = part[0][row][o] + part[1][row][o] +
                  part[2][row][o] + part[3][row][o];
        if (BIAS) v = (v + bias[o]) * scale;
        Y[((size_t)b * OO + o) * TT + (t0 + row)] = v;
    }
}

// ---------------------------------------------------------------------------
// K2: in-place softmax along T for each (b,o) column (contiguous, length 1024).
// ---------------------------------------------------------------------------
__global__ __launch_bounds__(256) void softmax_kernel(float* __restrict__ s)
{
    float* col = s + (size_t)blockIdx.x * TT;
    const int tid  = threadIdx.x;
    const int wave = tid >> 6;
    const int lane = tid & 63;

    float4 v = *(const float4*)(col + tid * 4);

    __shared__ float sm[4];
    __shared__ float ss[4];

    float m = fmaxf(fmaxf(v.x, v.y), fmaxf(v.z, v.w));
#pragma unroll
    for (int off = 32; off > 0; off >>= 1) m = fmaxf(m, __shfl_down(m, off, 64));
    if (lane == 0) sm[wave] = m;
    __syncthreads();
    m = fmaxf(fmaxf(sm[0], sm[1]), fmaxf(sm[2], sm[3]));

    float e0 = __expf(v.x - m), e1 = __expf(v.y - m);
    float e2 = __expf(v.z - m), e3 = __expf(v.w - m);
    float sum = e0 + e1 + e2 + e3;
#pragma unroll
    for (int off = 32; off > 0; off >>= 1) sum += __shfl_down(sum, off, 64);
    if (lane == 0) ss[wave] = sum;
    __syncthreads();
    const float inv = 1.0f / (ss[0] + ss[1] + ss[2] + ss[3]);

    *(float4*)(col + tid * 4) = make_float4(e0 * inv, e1 * inv, e2 * inv, e3 * inv);
}

extern "C" void kernel_launch(void* const* d_in, const int* in_sizes, int n_in,
                              void* d_out, int out_size, void* d_ws, size_t ws_size,
                              hipStream_t stream)
{
    const float* logits = (const float*)d_in[0];
    // d_in[1] = decision — unused by the forward math
    const float* W    = (const float*)d_in[2];
    const float* bias = (const float*)d_in[3];
    float* out    = (float*)d_out;
    float* scores = (float*)d_ws;  // B*O*T floats = 655 KB (softmax in-place)

    dim3 grid(TT / 32, BB);
    // K1: scores[b][o][t] = (logits[b,t,:] . W[o,:] + bias[o]) / O
    gemm10_kernel<true><<<grid, 256, 0, stream>>>(logits, W, bias, scores,
                                                  1.0f / OO, 0);
    // K2: softmax over t for each (b,o)
    softmax_kernel<<<BB * OO, 256, 0, stream>>>(scores);
    // K3: out[b][o][t] = logits[b,t,:] . w_x[b,:,o]  (w_x stored as (B,O,T))
    gemm10_kernel<false><<<grid, 256, 0, stream>>>(logits, scores, nullptr, out,
                                                   1.0f, 1);
}